// Round 1
// baseline (257.855 us; speedup 1.0000x reference)
//
#include <hip/hip_runtime.h>

// Problem constants
#define BB 4
#define LLL 256
#define LPP 256
#define DDIM 256
#define HH 128

typedef __bf16 bf16;
typedef bf16 bf16x8 __attribute__((ext_vector_type(8)));
typedef float floatx4 __attribute__((ext_vector_type(4)));

__device__ __forceinline__ float gelu_f(float x) {
    // x * sigmoid(1.702x): |err| vs erf-GELU < ~0.02, tolerance is 0.4 absolute.
    return x / (1.f + __expf(-1.702f * x));
}
__device__ __forceinline__ float sigmoid_f(float x) {
    return 1.f / (1.f + __expf(-x));
}

// ---------------------------------------------------------------------------
// Kernel 0: convert W1c|W1d (cols 512..1023 of W1) and W2 to bf16 in ws
// ---------------------------------------------------------------------------
__global__ void cvt_w(const float* __restrict__ W1, const float* __restrict__ W2,
                      bf16* __restrict__ w1cd, bf16* __restrict__ w2b) {
    int idx = blockIdx.x * 256 + threadIdx.x;
    if (idx < 128 * 512) {
        int h = idx >> 9, c = idx & 511;
        w1cd[idx] = (bf16)W1[h * 1024 + 512 + c];
    } else {
        int j = idx - 128 * 512;
        if (j < 128 * 128) w2b[j] = (bf16)W2[j];
    }
}

// ---------------------------------------------------------------------------
// Kernel 1: projections. proj[m][e], m in [0,1024): l rows, [1024,2048): p rows
// proj = tok @ W^T + bias  (bf16 out). Block tile 64x64, 4 waves, 16x16x32 MFMA
// ---------------------------------------------------------------------------
__global__ __launch_bounds__(256) void prep_proj(
    const float* __restrict__ l_tok, const float* __restrict__ p_tok,
    const float* __restrict__ Wl, const float* __restrict__ Wp,
    const float* __restrict__ bl, const float* __restrict__ bp,
    bf16* __restrict__ proj) {
    __shared__ __align__(16) char sm[2 * 64 * 80];
    bf16* As = (bf16*)sm;             // 64 x 40 (32 + 8 pad), stride 80B
    bf16* Bs = (bf16*)(sm + 64 * 80);
    int tid = threadIdx.x;
    int m0 = blockIdx.x * 64, n0 = blockIdx.y * 64;
    bool isP = (m0 >= 1024);
    const float* Asrc = isP ? (p_tok + (size_t)(m0 - 1024) * DDIM) : (l_tok + (size_t)m0 * DDIM);
    const float* Wsrc = isP ? Wp : Wl;
    const float* bias = isP ? bp : bl;
    int row = tid >> 2, seg = tid & 3;
    int w = tid >> 6, lane = tid & 63;
    int m16 = lane & 15, quad = lane >> 4;
    int wm = w & 1, wn = w >> 1;
    floatx4 acc[2][2];
#pragma unroll
    for (int a = 0; a < 2; ++a)
#pragma unroll
        for (int c = 0; c < 2; ++c) acc[a][c] = (floatx4)0.f;
    for (int k0 = 0; k0 < DDIM; k0 += 32) {
        float4 f0 = *(const float4*)(Asrc + row * DDIM + k0 + seg * 8);
        float4 f1 = *(const float4*)(Asrc + row * DDIM + k0 + seg * 8 + 4);
        bf16x8 av;
        av[0] = (bf16)f0.x; av[1] = (bf16)f0.y; av[2] = (bf16)f0.z; av[3] = (bf16)f0.w;
        av[4] = (bf16)f1.x; av[5] = (bf16)f1.y; av[6] = (bf16)f1.z; av[7] = (bf16)f1.w;
        *(bf16x8*)(As + row * 40 + seg * 8) = av;
        float4 g0 = *(const float4*)(Wsrc + (n0 + row) * DDIM + k0 + seg * 8);
        float4 g1 = *(const float4*)(Wsrc + (n0 + row) * DDIM + k0 + seg * 8 + 4);
        bf16x8 bv;
        bv[0] = (bf16)g0.x; bv[1] = (bf16)g0.y; bv[2] = (bf16)g0.z; bv[3] = (bf16)g0.w;
        bv[4] = (bf16)g1.x; bv[5] = (bf16)g1.y; bv[6] = (bf16)g1.z; bv[7] = (bf16)g1.w;
        *(bf16x8*)(Bs + row * 40 + seg * 8) = bv;
        __syncthreads();
        bf16x8 afr[2], bfr[2];
#pragma unroll
        for (int t = 0; t < 2; ++t)
            afr[t] = *(const bf16x8*)(As + (wm * 32 + t * 16 + m16) * 40 + quad * 8);
#pragma unroll
        for (int t = 0; t < 2; ++t)
            bfr[t] = *(const bf16x8*)(Bs + (wn * 32 + t * 16 + m16) * 40 + quad * 8);
#pragma unroll
        for (int a = 0; a < 2; ++a)
#pragma unroll
            for (int c = 0; c < 2; ++c)
                acc[a][c] = __builtin_amdgcn_mfma_f32_16x16x32_bf16(afr[a], bfr[c], acc[a][c], 0, 0, 0);
        __syncthreads();
    }
#pragma unroll
    for (int c = 0; c < 2; ++c) {
        int col = n0 + wn * 32 + c * 16 + m16;
        float bv = bias[col];
#pragma unroll
        for (int a = 0; a < 2; ++a) {
            int rbase = m0 + wm * 32 + a * 16 + quad * 4;
#pragma unroll
            for (int i = 0; i < 4; ++i)
                proj[(size_t)(rbase + i) * DDIM + col] = (bf16)(acc[a][c][i] + bv);
        }
    }
}

// ---------------------------------------------------------------------------
// Kernel 2: A/Bp. AB[m][h]: m<1024: A = l_proj @ W1a^T ; m>=1024: Bp = p_proj @ W1b^T
// fp32 out (becomes MFMA accumulator init in main kernel).
// ---------------------------------------------------------------------------
__global__ __launch_bounds__(256) void prep_ab(
    const bf16* __restrict__ proj, const float* __restrict__ W1,
    float* __restrict__ AB) {
    __shared__ __align__(16) char sm[2 * 64 * 80];
    bf16* As = (bf16*)sm;
    bf16* Bs = (bf16*)(sm + 64 * 80);
    int tid = threadIdx.x;
    int m0 = blockIdx.x * 64, n0 = blockIdx.y * 64;
    bool isP = (m0 >= 1024);
    int koff = isP ? 256 : 0;
    int row = tid >> 2, seg = tid & 3;
    int w = tid >> 6, lane = tid & 63;
    int m16 = lane & 15, quad = lane >> 4;
    int wm = w & 1, wn = w >> 1;
    floatx4 acc[2][2];
#pragma unroll
    for (int a = 0; a < 2; ++a)
#pragma unroll
        for (int c = 0; c < 2; ++c) acc[a][c] = (floatx4)0.f;
    for (int k0 = 0; k0 < DDIM; k0 += 32) {
        bf16x8 av = *(const bf16x8*)(proj + (size_t)(m0 + row) * DDIM + k0 + seg * 8);
        *(bf16x8*)(As + row * 40 + seg * 8) = av;
        float4 g0 = *(const float4*)(W1 + (size_t)(n0 + row) * 1024 + koff + k0 + seg * 8);
        float4 g1 = *(const float4*)(W1 + (size_t)(n0 + row) * 1024 + koff + k0 + seg * 8 + 4);
        bf16x8 bv;
        bv[0] = (bf16)g0.x; bv[1] = (bf16)g0.y; bv[2] = (bf16)g0.z; bv[3] = (bf16)g0.w;
        bv[4] = (bf16)g1.x; bv[5] = (bf16)g1.y; bv[6] = (bf16)g1.z; bv[7] = (bf16)g1.w;
        *(bf16x8*)(Bs + row * 40 + seg * 8) = bv;
        __syncthreads();
        bf16x8 afr[2], bfr[2];
#pragma unroll
        for (int t = 0; t < 2; ++t)
            afr[t] = *(const bf16x8*)(As + (wm * 32 + t * 16 + m16) * 40 + quad * 8);
#pragma unroll
        for (int t = 0; t < 2; ++t)
            bfr[t] = *(const bf16x8*)(Bs + (wn * 32 + t * 16 + m16) * 40 + quad * 8);
#pragma unroll
        for (int a = 0; a < 2; ++a)
#pragma unroll
            for (int c = 0; c < 2; ++c)
                acc[a][c] = __builtin_amdgcn_mfma_f32_16x16x32_bf16(afr[a], bfr[c], acc[a][c], 0, 0, 0);
        __syncthreads();
    }
#pragma unroll
    for (int c = 0; c < 2; ++c) {
        int col = n0 + wn * 32 + c * 16 + m16;
#pragma unroll
        for (int a = 0; a < 2; ++a) {
            int rbase = m0 + wm * 32 + a * 16 + quad * 4;
#pragma unroll
            for (int i = 0; i < 4; ++i)
                AB[(size_t)(rbase + i) * HH + col] = acc[a][c][i];
        }
    }
}

// ---------------------------------------------------------------------------
// Kernel 3: main pair kernel. One block per (b,l). 512 threads = 8 waves.
// GEMM1: h1 = gelu(A + Bp + b1 + [l*p]@W1c^T + [|l-p|]@W1d^T)  (256p x 128h, K=512)
// GEMM2: h2 = gelu(h1 @ W2^T + b2); logit = h2 . W3 + b3; mask; sigmoid.
// ---------------------------------------------------------------------------
// LDS layout (bytes):
#define SM_W2S 0          // 128 x 136 bf16 = 34816 (persistent)
#define SM_LSH 34816      // 256 bf16 = 512
#define SM_ASH 35328      // 128 f32 = 512
#define SM_PLOG 35840     // 256 f32 = 1024
#define SM_U 36864        // union region
#define SM_XSA (SM_U)             // 256 x 40 bf16 = 20480
#define SM_XSB (SM_U + 20480)     // 20480
#define SM_WC (SM_U + 40960)      // 128 x 40 bf16 = 10240
#define SM_WD (SM_U + 51200)      // 10240
#define SM_H1 (SM_U)              // 256 x 136 bf16 = 69632 (phase 2, overlaps)
#define SM_TOTAL 106496

__global__ __launch_bounds__(512, 2) void pair_main(
    const bf16* __restrict__ proj, const float* __restrict__ AB,
    const bf16* __restrict__ w1cd, const bf16* __restrict__ w2b,
    const float* __restrict__ b1, const float* __restrict__ b2,
    const float* __restrict__ W3, const float* __restrict__ b3,
    const int* __restrict__ l_pad, const int* __restrict__ p_pad,
    float* __restrict__ out) {
    __shared__ __align__(16) char sm[SM_TOTAL];
    int tid = threadIdx.x;
    int l = blockIdx.x, b = blockIdx.y;
    float* outPL = out + 4;
    float* outPR = out + 4 + BB * LLL * LPP;
    size_t rowbase = ((size_t)(b * LLL + l)) * LPP;

    if (l_pad[b * LLL + l] != 0) {
        float pr = sigmoid_f(-20.f);
        if (tid < LPP) {
            outPL[rowbase + tid] = -20.f;
            outPR[rowbase + tid] = pr;
        }
        return;
    }

    bf16* w2s = (bf16*)(sm + SM_W2S);
    bf16* lsh = (bf16*)(sm + SM_LSH);
    float* ash = (float*)(sm + SM_ASH);
    float* plog = (float*)(sm + SM_PLOG);
    bf16* xsa = (bf16*)(sm + SM_XSA);
    bf16* xsb = (bf16*)(sm + SM_XSB);
    bf16* wcs = (bf16*)(sm + SM_WC);
    bf16* wds = (bf16*)(sm + SM_WD);
    bf16* h1s = (bf16*)(sm + SM_H1);

    int lane = tid & 63, w = tid >> 6;
    int m16 = lane & 15, quad = lane >> 4;
    int wp = w & 3, wh = w >> 2;
    int p0 = wp * 64, h0 = wh * 64;

    // stage W2 -> LDS (region disjoint from phase-1 buffers)
    {
        int g = tid >> 2, c0 = (tid & 3) * 32;
#pragma unroll
        for (int j = 0; j < 4; ++j) {
            bf16x8 v = *(const bf16x8*)(w2b + g * HH + c0 + j * 8);
            *(bf16x8*)(w2s + g * 136 + c0 + j * 8) = v;
        }
    }
    if (tid < 32)
        *(bf16x8*)(lsh + tid * 8) = *(const bf16x8*)(proj + ((size_t)(b * LLL + l)) * DDIM + tid * 8);
    if (tid < 128) ash[tid] = AB[(size_t)(b * LLL + l) * HH + tid] + b1[tid];
    if (tid < 256) plog[tid] = 0.f;

    // prefetch d-step 0 (P slices + W tiles into regs)
    int kg = tid & 3, prow = tid >> 2;
    const bf16* Pbase = proj + (size_t)(1024 + b * LPP) * DDIM;
    int hW = tid >> 2, ck = tid & 3;
    bf16x8 Pv0 = *(const bf16x8*)(Pbase + prow * DDIM + kg * 8);
    bf16x8 Pv1 = *(const bf16x8*)(Pbase + (prow + 128) * DDIM + kg * 8);
    bf16x8 Wcv = *(const bf16x8*)(w1cd + hW * 512 + ck * 8);
    bf16x8 Wdv = *(const bf16x8*)(w1cd + hW * 512 + 256 + ck * 8);

    __syncthreads();

    // accumulator init: A[l,h] + b1[h] + Bp[p,h]
    floatx4 acc[4][4];
    float av4[4];
#pragma unroll
    for (int th = 0; th < 4; ++th) av4[th] = ash[h0 + th * 16 + m16];
    const float* Bp = AB + (size_t)(1024 + b * LPP) * HH;
#pragma unroll
    for (int tp = 0; tp < 4; ++tp) {
        int rp = p0 + tp * 16 + quad * 4;
#pragma unroll
        for (int th = 0; th < 4; ++th) {
            int chh = h0 + th * 16 + m16;
            floatx4 a;
#pragma unroll
            for (int i = 0; i < 4; ++i) a[i] = Bp[(size_t)(rp + i) * HH + chh] + av4[th];
            acc[tp][th] = a;
        }
    }

    // GEMM1 K-loop: 8 d-steps of 32 (t1 and t2 simultaneously, K=512 total)
    for (int ds = 0; ds < 8; ++ds) {
        *(bf16x8*)(wcs + hW * 40 + ck * 8) = Wcv;
        *(bf16x8*)(wds + hW * 40 + ck * 8) = Wdv;
        bf16x8 lv = *(const bf16x8*)(lsh + ds * 32 + kg * 8);
        float lf[8];
#pragma unroll
        for (int i = 0; i < 8; ++i) lf[i] = (float)lv[i];
        {
            bf16x8 x1, x2;
#pragma unroll
            for (int i = 0; i < 8; ++i) {
                float pf = (float)Pv0[i];
                x1[i] = (bf16)(lf[i] * pf);
                x2[i] = (bf16)fabsf(lf[i] - pf);
            }
            *(bf16x8*)(xsa + prow * 40 + kg * 8) = x1;
            *(bf16x8*)(xsb + prow * 40 + kg * 8) = x2;
#pragma unroll
            for (int i = 0; i < 8; ++i) {
                float pf = (float)Pv1[i];
                x1[i] = (bf16)(lf[i] * pf);
                x2[i] = (bf16)fabsf(lf[i] - pf);
            }
            *(bf16x8*)(xsa + (prow + 128) * 40 + kg * 8) = x1;
            *(bf16x8*)(xsb + (prow + 128) * 40 + kg * 8) = x2;
        }
        int dn = (ds + 1) & 7;  // prefetch next (harmless wrap on last iter)
        Pv0 = *(const bf16x8*)(Pbase + prow * DDIM + dn * 32 + kg * 8);
        Pv1 = *(const bf16x8*)(Pbase + (prow + 128) * DDIM + dn * 32 + kg * 8);
        Wcv = *(const bf16x8*)(w1cd + hW * 512 + dn * 32 + ck * 8);
        Wdv = *(const bf16x8*)(w1cd + hW * 512 + 256 + dn * 32 + ck * 8);
        __syncthreads();
        bf16x8 a1[4], a2[4], bc[4], bd[4];
#pragma unroll
        for (int tp = 0; tp < 4; ++tp) {
            a1[tp] = *(const bf16x8*)(xsa + (p0 + tp * 16 + m16) * 40 + quad * 8);
            a2[tp] = *(const bf16x8*)(xsb + (p0 + tp * 16 + m16) * 40 + quad * 8);
        }
#pragma unroll
        for (int th = 0; th < 4; ++th) {
            bc[th] = *(const bf16x8*)(wcs + (h0 + th * 16 + m16) * 40 + quad * 8);
            bd[th] = *(const bf16x8*)(wds + (h0 + th * 16 + m16) * 40 + quad * 8);
        }
#pragma unroll
        for (int tp = 0; tp < 4; ++tp)
#pragma unroll
            for (int th = 0; th < 4; ++th) {
                acc[tp][th] = __builtin_amdgcn_mfma_f32_16x16x32_bf16(a1[tp], bc[th], acc[tp][th], 0, 0, 0);
                acc[tp][th] = __builtin_amdgcn_mfma_f32_16x16x32_bf16(a2[tp], bd[th], acc[tp][th], 0, 0, 0);
            }
        __syncthreads();
    }

    // epilogue 1: GELU -> h1s (overlaps dead phase-1 buffers; barrier above protects)
#pragma unroll
    for (int tp = 0; tp < 4; ++tp) {
        int rp = p0 + tp * 16 + quad * 4;
#pragma unroll
        for (int th = 0; th < 4; ++th) {
            int chh = h0 + th * 16 + m16;
#pragma unroll
            for (int i = 0; i < 4; ++i)
                h1s[(rp + i) * 136 + chh] = (bf16)gelu_f(acc[tp][th][i]);
        }
    }
    __syncthreads();

    // GEMM2: 256p x 128g, K=128
    float b2v[4], w3v[4];
#pragma unroll
    for (int th = 0; th < 4; ++th) {
        int cg = h0 + th * 16 + m16;
        b2v[th] = b2[cg];
        w3v[th] = W3[cg];
    }
    floatx4 acc2[4][4];
#pragma unroll
    for (int tp = 0; tp < 4; ++tp)
#pragma unroll
        for (int th = 0; th < 4; ++th) {
            floatx4 a;
            a[0] = a[1] = a[2] = a[3] = b2v[th];
            acc2[tp][th] = a;
        }
    for (int ks = 0; ks < 4; ++ks) {
        bf16x8 af[4], bfm[4];
#pragma unroll
        for (int tp = 0; tp < 4; ++tp)
            af[tp] = *(const bf16x8*)(h1s + (p0 + tp * 16 + m16) * 136 + ks * 32 + quad * 8);
#pragma unroll
        for (int th = 0; th < 4; ++th)
            bfm[th] = *(const bf16x8*)(w2s + (h0 + th * 16 + m16) * 136 + ks * 32 + quad * 8);
#pragma unroll
        for (int tp = 0; tp < 4; ++tp)
#pragma unroll
            for (int th = 0; th < 4; ++th)
                acc2[tp][th] = __builtin_amdgcn_mfma_f32_16x16x32_bf16(af[tp], bfm[th], acc2[tp][th], 0, 0, 0);
    }

    // epilogue 2: GELU, partial W3-dot, cross-lane reduce, accumulate to plog
    float part[16];
#pragma unroll
    for (int j = 0; j < 16; ++j) part[j] = 0.f;
#pragma unroll
    for (int tp = 0; tp < 4; ++tp)
#pragma unroll
        for (int th = 0; th < 4; ++th)
#pragma unroll
            for (int i = 0; i < 4; ++i) {
                float h2 = gelu_f(acc2[tp][th][i]);
                part[tp * 4 + i] += w3v[th] * h2;
            }
#pragma unroll
    for (int mask = 1; mask <= 8; mask <<= 1)
#pragma unroll
        for (int j = 0; j < 16; ++j) part[j] += __shfl_xor(part[j], mask, 64);
    if (m16 == 0) {
#pragma unroll
        for (int tp = 0; tp < 4; ++tp)
#pragma unroll
            for (int i = 0; i < 4; ++i)
                atomicAdd(&plog[p0 + tp * 16 + quad * 4 + i], part[tp * 4 + i]);
    }
    __syncthreads();

    if (tid < LPP) {
        int p = tid;
        float pl = plog[p] + b3[0];
        if (__builtin_isnan(pl)) pl = 0.f;
        else if (__builtin_isinf(pl)) pl = pl > 0.f ? 20.f : -20.f;
        if (p_pad[b * LPP + p] != 0) pl = -20.f;
        outPL[rowbase + p] = pl;
        outPR[rowbase + p] = sigmoid_f(pl);
    }
}

// ---------------------------------------------------------------------------
// Kernel 4: exact top-100 + softmax pool per batch. 1 block per b, 1024 thr.
// Register-resident 4-pass radix select on order-preserving u32 keys.
// ---------------------------------------------------------------------------
__global__ __launch_bounds__(1024) void topk_k(const float* __restrict__ pl,
                                               float* __restrict__ out) {
    __shared__ int hist[512];
    __shared__ float redf[32];
    __shared__ unsigned bc_pref;
    __shared__ int bc_rem;
    __shared__ float bc_vmax;
    int b = blockIdx.x, tid = threadIdx.x;
    int wv = tid >> 6, lane = tid & 63;
    const float* src = pl + (size_t)b * 65536;
    float v[64];
#pragma unroll
    for (int j = 0; j < 16; ++j) {
        float4 t = ((const float4*)src)[tid + j * 1024];
        v[j * 4 + 0] = t.x; v[j * 4 + 1] = t.y; v[j * 4 + 2] = t.z; v[j * 4 + 3] = t.w;
    }
    float mx = v[0];
#pragma unroll
    for (int j = 1; j < 64; ++j) mx = fmaxf(mx, v[j]);
    for (int off = 32; off > 0; off >>= 1) mx = fmaxf(mx, __shfl_xor(mx, off, 64));
    if (lane == 0) redf[wv] = mx;
    __syncthreads();
    if (tid == 0) {
        float m = redf[0];
        for (int i = 1; i < 16; ++i) m = fmaxf(m, redf[i]);
        bc_vmax = m;
    }
    unsigned pref = 0;
    int rem = 100;
    for (int pass = 0; pass < 4; ++pass) {
        if (tid < 512) hist[tid] = 0;
        __syncthreads();
        int sh = 24 - 8 * pass;
        int rep = (wv & 1) * 256;
#pragma unroll
        for (int j = 0; j < 64; ++j) {
            unsigned u = __float_as_uint(v[j]);
            u = (u & 0x80000000u) ? ~u : (u | 0x80000000u);
            bool in = (pass == 0) || ((u >> (sh + 8)) == pref);
            if (in) atomicAdd(&hist[((u >> sh) & 255) + rep], 1);
        }
        __syncthreads();
        if (tid == 0) {
            int cum = 0, chosen = 0, above = 0;
            for (int bin = 255; bin >= 0; --bin) {
                int c = hist[bin] + hist[bin + 256];
                if (cum + c >= rem) { chosen = bin; above = cum; break; }
                cum += c;
            }
            bc_pref = (pref << 8) | (unsigned)chosen;
            bc_rem = rem - above;
        }
        __syncthreads();
        pref = bc_pref;
        rem = bc_rem;
        __syncthreads();
    }
    float vmax = bc_vmax;
    float s1 = 0.f, s2 = 0.f;
#pragma unroll
    for (int j = 0; j < 64; ++j) {
        unsigned u = __float_as_uint(v[j]);
        u = (u & 0x80000000u) ? ~u : (u | 0x80000000u);
        if (u > pref) {
            float e = __expf(v[j] - vmax);
            s1 += e;
            s2 += e * v[j];
        }
    }
    for (int off = 32; off > 0; off >>= 1) {
        s1 += __shfl_xor(s1, off, 64);
        s2 += __shfl_xor(s2, off, 64);
    }
    if (lane == 0) { redf[wv] = s1; redf[16 + wv] = s2; }
    __syncthreads();
    if (tid == 0) {
        float t1 = 0.f, t2 = 0.f;
        for (int i = 0; i < 16; ++i) { t1 += redf[i]; t2 += redf[16 + i]; }
        unsigned bits = (pref & 0x80000000u) ? (pref & 0x7fffffffu) : ~pref;
        float vT = __uint_as_float(bits);
        float e = __expf(vT - vmax);
        t1 += (float)rem * e;
        t2 += (float)rem * e * vT;
        out[b] = t2 / t1;
    }
}

// ---------------------------------------------------------------------------
extern "C" void kernel_launch(void* const* d_in, const int* in_sizes, int n_in,
                              void* d_out, int out_size, void* d_ws, size_t ws_size,
                              hipStream_t stream) {
    const float* l_tok = (const float*)d_in[0];
    const float* p_tok = (const float*)d_in[1];
    const int* l_pad = (const int*)d_in[2];
    const int* p_pad = (const int*)d_in[3];
    const float* Wl = (const float*)d_in[4];
    const float* bl = (const float*)d_in[5];
    const float* Wp = (const float*)d_in[6];
    const float* bp = (const float*)d_in[7];
    const float* W1 = (const float*)d_in[8];
    const float* b1 = (const float*)d_in[9];
    const float* W2 = (const float*)d_in[10];
    const float* b2 = (const float*)d_in[11];
    const float* W3 = (const float*)d_in[12];
    const float* b3 = (const float*)d_in[13];
    float* out = (float*)d_out;

    char* ws = (char*)d_ws;
    bf16* proj = (bf16*)ws;                                   // 2048*256 bf16 = 1 MiB
    float* AB = (float*)(ws + (size_t)2048 * 256 * 2);        // 2048*128 f32 = 1 MiB
    bf16* w1cd = (bf16*)(ws + (size_t)2048 * 256 * 2 + (size_t)2048 * 128 * 4);  // 128*512 bf16
    bf16* w2b = (bf16*)((char*)w1cd + (size_t)128 * 512 * 2); // 128*128 bf16

    cvt_w<<<320, 256, 0, stream>>>(W1, W2, w1cd, w2b);
    prep_proj<<<dim3(32, 4), 256, 0, stream>>>(l_tok, p_tok, Wl, Wp, bl, bp, proj);
    prep_ab<<<dim3(32, 2), 256, 0, stream>>>(proj, W1, AB);
    pair_main<<<dim3(LLL, BB), 512, 0, stream>>>(proj, AB, w1cd, w2b, b1, b2, W3, b3,
                                                 l_pad, p_pad, out);
    topk_k<<<BB, 1024, 0, stream>>>(out + 4, out);
}